// Round 3
// baseline (24.269 us; speedup 1.0000x reference)
//
#include <hip/hip_runtime.h>
#include <math.h>

#define EPSF 1e-8f

constexpr int B = 512;
constexpr int F = 256;
constexpr int NTHREADS = 256;

using frag_ab = __attribute__((ext_vector_type(8))) short;   // 8 bf16
using frag_cd = __attribute__((ext_vector_type(4))) float;   // 4 fp32

__device__ __forceinline__ unsigned short f2bf(float f) {
    unsigned int u = __float_as_uint(f);
    unsigned int r = (u + 0x7fffu + ((u >> 16) & 1u)) >> 16;   // RNE
    return (unsigned short)r;
}

// ---------------- K1: fused norms + bf16-MFMA cos, one 32x32 tile per block ----
__global__ __launch_bounds__(256) void cos_mfma_kernel(
    const float* __restrict__ feats, float* __restrict__ cosm,
    int* __restrict__ ticket)
{
    const int it = blockIdx.y, jt = blockIdx.x;
    const int tid = threadIdx.x;

    __shared__ __align__(16) unsigned short Abf[32 * 256];  // 16 KB, swizzled
    __shared__ __align__(16) unsigned short Bbf[32 * 256];  // 16 KB, swizzled
    __shared__ float invA_s[32], invB_s[32];

    if (it == 0 && jt == 0 && tid == 0) *ticket = 0;   // reset for K2's last-block pattern

    // ---- stage A and B panels: fp32 global -> bf16 LDS (XOR-swizzled 16B chunks)
    const float4* Ag = (const float4*)(feats + (size_t)(it * 32) * F);
    const float4* Bg = (const float4*)(feats + (size_t)(jt * 32) * F);
    #pragma unroll
    for (int q = 0; q < 8; ++q) {
        int idx = tid + 256 * q;          // 2048 float4 per panel
        int r = idx >> 6, c = idx & 63;   // row 0..31, f4-col 0..63
        int chunk = (c >> 1) ^ (r & 7);   // swizzle 16B chunk index
        size_t doff = (size_t)r * 512 + (size_t)chunk * 16 + (size_t)(c & 1) * 8;

        float4 a = Ag[r * 64 + c];
        ushort4 ha = { f2bf(a.x), f2bf(a.y), f2bf(a.z), f2bf(a.w) };
        *(ushort4*)((char*)Abf + doff) = ha;

        float4 b = Bg[r * 64 + c];
        ushort4 hb = { f2bf(b.x), f2bf(b.y), f2bf(b.z), f2bf(b.w) };
        *(ushort4*)((char*)Bbf + doff) = hb;
    }

    // ---- fp32-exact inverse norms (global rows are L1-hot from staging)
    {
        int r_all = tid >> 2, p = tid & 3;            // 64 rows (A:0..31, B:32..63)
        const float4* Rg = (const float4*)(feats +
            (size_t)((r_all < 32 ? it * 32 + r_all : jt * 32 + (r_all - 32))) * F);
        float ss = 0.f;
        #pragma unroll
        for (int m = 0; m < 16; ++m) {
            float4 v = Rg[p * 16 + m];
            ss += v.x*v.x + v.y*v.y + v.z*v.z + v.w*v.w;
        }
        ss += __shfl_xor(ss, 1);
        ss += __shfl_xor(ss, 2);
        if (p == 0) {
            float inv = 1.f / fmaxf(sqrtf(ss + EPSF), EPSF);
            if (r_all < 32) invA_s[r_all] = inv; else invB_s[r_all - 32] = inv;
        }
    }
    __syncthreads();

    // ---- MFMA: wave w owns 16x16 sub-tile (w>>1, w&1); gemm_bt fragments
    const int l = tid & 63, w = tid >> 6;
    const int RA = (w >> 1) * 16, CB = (w & 1) * 16;
    const int arow = RA + (l & 15), brow = CB + (l & 15);
    const int csub = l >> 4;                           // 0..3 k-group

    frag_cd acc = {0.f, 0.f, 0.f, 0.f};
    #pragma unroll
    for (int kc = 0; kc < 8; ++kc) {
        int ca = (kc * 4 + csub) ^ (arow & 7);
        int cb = (kc * 4 + csub) ^ (brow & 7);
        frag_ab a = *(const frag_ab*)((const char*)Abf + arow * 512 + ca * 16);
        frag_ab b = *(const frag_ab*)((const char*)Bbf + brow * 512 + cb * 16);
        acc = __builtin_amdgcn_mfma_f32_16x16x32_bf16(a, b, acc, 0, 0, 0);
    }

    // ---- epilogue: C layout col=lane&15, row=(lane>>4)*4+j; apply invn at write
    const int col = l & 15;
    const int gj = jt * 32 + CB + col;
    const float invb = invB_s[CB + col];
    #pragma unroll
    for (int j = 0; j < 4; ++j) {
        int row = csub * 4 + j;
        float v = acc[j] * invA_s[RA + row] * invb;
        cosm[(size_t)(it * 32 + RA + row) * B + gj] = v;
    }
}

// ---------------- K2: per-row hinge sums + last-block finalize ----------------
__global__ __launch_bounds__(256) void rows_kernel(
    const int* __restrict__ ids, const float* __restrict__ cosm,
    float* __restrict__ rowloss, int* __restrict__ rowvalid,
    int* __restrict__ ticket, float* __restrict__ out)
{
    const int i    = blockIdx.x;
    const int tid  = threadIdx.x;
    const int lane = tid & 63;
    const int wid  = tid >> 6;

    __shared__ int   dd[B];
    __shared__ float vals[B];
    __shared__ unsigned long long cmask[8];
    __shared__ int   coff[9];
    __shared__ float part_s[4], part_n[4];
    __shared__ int   lastflag;

    const int4 idi = ((const int4*)ids)[i];
    #pragma unroll
    for (int jj = 0; jj < B / NTHREADS; ++jj) {
        int j = tid + jj * NTHREADS;
        int4 idj = ((const int4*)ids)[j];
        dd[j] = abs(idi.x - idj.x) + abs(idi.y - idj.y)
              + abs(idi.z - idj.z) + abs(idi.w - idj.w);
    }
    __syncthreads();

    // ballot-compact sim set {j : dd[j]==0, j!=i}
    #pragma unroll
    for (int cc = 0; cc < 2; ++cc) {
        int chunk = wid * 2 + cc;
        int j = chunk * 64 + lane;
        unsigned long long m = __ballot((dd[j] == 0) && (j != i));
        if (lane == 0) cmask[chunk] = m;
    }
    __syncthreads();
    if (tid == 0) {
        int acc = 0;
        #pragma unroll
        for (int cch = 0; cch < 8; ++cch) { coff[cch] = acc; acc += (int)__popcll(cmask[cch]); }
        coff[8] = acc;
    }
    __syncthreads();
    #pragma unroll
    for (int cc = 0; cc < 2; ++cc) {
        int chunk = wid * 2 + cc;
        int j = chunk * 64 + lane;
        unsigned long long m = cmask[chunk];
        if ((m >> lane) & 1ull) {
            int pos = coff[chunk] + (int)__popcll(m & ((1ull << lane) - 1ull));
            vals[pos] = cosm[(size_t)i * B + j];
        }
    }
    __syncthreads();

    const int ns = coff[8];
    const int d0 = dd[tid], d1 = dd[tid + NTHREADS];
    const bool m0 = d0 > 0, m1 = d1 > 0;
    const float b0 = 0.15f * (float)d0 + cosm[(size_t)i * B + tid];
    const float b1 = 0.15f * (float)d1 + cosm[(size_t)i * B + tid + NTHREADS];

    float s   = 0.f;
    float ndf = (m0 ? 1.f : 0.f) + (m1 ? 1.f : 0.f);
    for (int t = 0; t < ns; ++t) {
        float a = vals[t];
        if (m0) s += fmaxf(0.f, b0 - a);
        if (m1) s += fmaxf(0.f, b1 - a);
    }

    #pragma unroll
    for (int off = 32; off > 0; off >>= 1) {
        s   += __shfl_down(s, off);
        ndf += __shfl_down(ndf, off);
    }
    if (lane == 0) { part_s[wid] = s; part_n[wid] = ndf; }
    __syncthreads();
    if (tid == 0) {
        float tot = part_s[0] + part_s[1] + part_s[2] + part_s[3];
        float nd  = part_n[0] + part_n[1] + part_n[2] + part_n[3];
        float cnt = (float)ns * nd;
        rowloss[i]  = (cnt > 0.f) ? tot / cnt : 0.f;
        rowvalid[i] = (cnt > 0.f) ? 1 : 0;
        __threadfence();                       // device-scope release of the stores above
        int old = atomicAdd(ticket, 1);
        lastflag = (old == B - 1);
    }
    __syncthreads();
    if (!lastflag) return;

    // last block: deterministic fixed-order reduce over all rows (coherent reads)
    float fs = atomicAdd(&rowloss[tid], 0.f) + atomicAdd(&rowloss[tid + NTHREADS], 0.f);
    float fv = (float)(atomicAdd(&rowvalid[tid], 0) + atomicAdd(&rowvalid[tid + NTHREADS], 0));
    #pragma unroll
    for (int off = 32; off > 0; off >>= 1) {
        fs += __shfl_down(fs, off);
        fv += __shfl_down(fv, off);
    }
    __syncthreads();
    if (lane == 0) { part_s[wid] = fs; part_n[wid] = fv; }
    __syncthreads();
    if (tid == 0) {
        float ts = part_s[0] + part_s[1] + part_s[2] + part_s[3];
        float tv = part_n[0] + part_n[1] + part_n[2] + part_n[3];
        out[0] = ts / fmaxf(tv, 1.f);
    }
}

extern "C" void kernel_launch(void* const* d_in, const int* in_sizes, int n_in,
                              void* d_out, int out_size, void* d_ws, size_t ws_size,
                              hipStream_t stream) {
    const int*   ids   = (const int*)d_in[0];
    const float* feats = (const float*)d_in[1];
    float* out = (float*)d_out;

    char* ws = (char*)d_ws;
    float* cosm     = (float*)ws;                               // 1 MB
    float* rowloss  = (float*)(ws + (size_t)B * B * 4);         // 2 KB
    int*   rowvalid = (int*)  (ws + (size_t)B * B * 4 + 2048);  // 2 KB
    int*   ticket   = (int*)  (ws + (size_t)B * B * 4 + 4096);

    hipLaunchKernelGGL(cos_mfma_kernel, dim3(16, 16), dim3(NTHREADS), 0, stream,
                       feats, cosm, ticket);
    hipLaunchKernelGGL(rows_kernel, dim3(B), dim3(NTHREADS), 0, stream,
                       ids, cosm, rowloss, rowvalid, ticket, out);
}